// Round 12
// baseline (194.742 us; speedup 1.0000x reference)
//
#include <hip/hip_runtime.h>

// SememeEmbeddingKNN — sid-sorted phase A (counting sort) + fused select/out.
//   emb      [V=50257, H=1024] f32   (206 MB table)
//   word_ids [L=256, W=16]     i32
//   sem_ids  [L=256, W=16, S=32] i32
//   out      [L, H] f32
//
// R11 -> R12: random-row gathers cap at ~2.8-4 TB/s HBM and refetch 1.7x
// (331 MB warm). Fix: counting-sort jobs by sid, then phase A walks jobs in
// ascending-sid order -> table streamed ~once sequentially (192 MB unique),
// word rows (16 MB) cache-resident. Sort = hist + 1-block scan + scatter
// (all tiny). dist[j] is per-job-slot -> d_out deterministic regardless of
// intra-bucket scatter order.
// BC: select (strict '>', earliest index on ties = jax top_k) fused with
// float4 gather/accumulate. No atomics on outputs, no out memset.

#define HDIM 1024
#define SNUM 32
#define WNUM 16
#define KNN  3
#define SCAN_T 1024
#define SCAN_CHUNK 50   // ceil(50257/1024)

// ---------------- Sort 1: histogram of sememe ids ----------------
__global__ __launch_bounds__(256) void knn_hist_kernel(
    const int* __restrict__ sem_ids, int* __restrict__ hist, int nj)
{
    const int j = blockIdx.x * 256 + threadIdx.x;
    if (j < nj) atomicAdd(&hist[sem_ids[j]], 1);
}

// ---------------- Sort 2: single-block exclusive scan -> cursor ----------
__global__ __launch_bounds__(SCAN_T) void knn_scan_kernel(
    const int* __restrict__ hist, int* __restrict__ cursor, int V)
{
    const int t = threadIdx.x;
    int vals[SCAN_CHUNK];
    const int base = t * SCAN_CHUNK;
    int sum = 0;
    #pragma unroll
    for (int i = 0; i < SCAN_CHUNK; ++i) {
        const int v = base + i;
        vals[i] = sum;                      // local exclusive prefix
        sum += (v < V) ? hist[v] : 0;
    }
    __shared__ int tot[SCAN_T];
    tot[t] = sum;
    __syncthreads();
    for (int off = 1; off < SCAN_T; off <<= 1) {
        const int x = (t >= off) ? tot[t - off] : 0;
        __syncthreads();
        tot[t] += x;
        __syncthreads();
    }
    const int myoff = (t == 0) ? 0 : tot[t - 1];
    #pragma unroll
    for (int i = 0; i < SCAN_CHUNK; ++i) {
        const int v = base + i;
        if (v < V) cursor[v] = myoff + vals[i];
    }
}

// ---------------- Sort 3: scatter job ids into sorted order ----------------
__global__ __launch_bounds__(256) void knn_scatter_kernel(
    const int* __restrict__ sem_ids, int* __restrict__ cursor,
    int* __restrict__ perm, int nj)
{
    const int j = blockIdx.x * 256 + threadIdx.x;
    if (j < nj) {
        const int pos = atomicAdd(&cursor[sem_ids[j]], 1);
        perm[pos] = j;
    }
}

// ------------- Phase A: distances, jobs in ascending-sid order -------------
__global__ __launch_bounds__(256) void knn_dist_sorted_kernel(
    const float* __restrict__ emb,
    const int*   __restrict__ word_ids,
    const int*   __restrict__ sem_ids,
    const int*   __restrict__ perm,
    float*       __restrict__ dist)
{
    const int wave = threadIdx.x >> 6;
    const int lane = threadIdx.x & 63;
    const int g    = blockIdx.x * 4 + wave;     // sorted-order wave index

    const int j   = perm[g];                    // broadcast (uniform addr)
    const int b   = j >> 5;
    const int sid = sem_ids[j];
    const int wid = word_ids[b];

    const float* srow = emb + (size_t)sid * HDIM + 4 * lane;
    const float* wrow = emb + (size_t)wid * HDIM + 4 * lane;

    // 8 independent float4 loads: full s row (streamed, sorted) + w row
    // (16 MB footprint, cache-resident).
    const float4 s0 = *(const float4*)(srow + 0);
    const float4 s1 = *(const float4*)(srow + 256);
    const float4 s2 = *(const float4*)(srow + 512);
    const float4 s3 = *(const float4*)(srow + 768);
    const float4 w0 = *(const float4*)(wrow + 0);
    const float4 w1 = *(const float4*)(wrow + 256);
    const float4 w2 = *(const float4*)(wrow + 512);
    const float4 w3 = *(const float4*)(wrow + 768);

    float d = 0.0f;
    {
        const float dx = s0.x - w0.x, dy = s0.y - w0.y, dz = s0.z - w0.z, dw = s0.w - w0.w;
        d += dx * dx + dy * dy + dz * dz + dw * dw;
    }
    {
        const float dx = s1.x - w1.x, dy = s1.y - w1.y, dz = s1.z - w1.z, dw = s1.w - w1.w;
        d += dx * dx + dy * dy + dz * dz + dw * dw;
    }
    {
        const float dx = s2.x - w2.x, dy = s2.y - w2.y, dz = s2.z - w2.z, dw = s2.w - w2.w;
        d += dx * dx + dy * dy + dz * dz + dw * dw;
    }
    {
        const float dx = s3.x - w3.x, dy = s3.y - w3.y, dz = s3.z - w3.z, dw = s3.w - w3.w;
        d += dx * dx + dy * dy + dz * dz + dw * dw;
    }

    #pragma unroll
    for (int off = 32; off >= 1; off >>= 1)
        d += __shfl_xor(d, off, 64);

    if (lane == 0) dist[j] = d;
}

// ------------- Phase BC: select (top-3) + gather/accumulate, fused --------
__global__ __launch_bounds__(256) void knn_outsel_kernel(
    const float* __restrict__ emb,
    const float* __restrict__ dist,        // [nj]
    const int*   __restrict__ word_ids,
    const int*   __restrict__ sem_ids,
    float*       __restrict__ out)
{
    const int l = blockIdx.x;
    const int t = threadIdx.x;

    __shared__ int s_ids[WNUM * 4];

    // Stage 1: threads 0..15 each select for one word.
    if (t < WNUM) {
        const int b = l * WNUM + t;
        float dl[SNUM];
        const float4* p = (const float4*)(dist + b * SNUM);
        #pragma unroll
        for (int i = 0; i < 8; ++i) {
            const float4 v = p[i];
            dl[4 * i + 0] = v.x;
            dl[4 * i + 1] = v.y;
            dl[4 * i + 2] = v.z;
            dl[4 * i + 3] = v.w;
        }
        // Top-3 descending; strict '>' keeps earliest index (= jax top_k).
        unsigned chosen = 0;
        #pragma unroll
        for (int k = 0; k < KNN; ++k) {
            float best = -1.0f;
            int   bi   = 0;
            #pragma unroll
            for (int s = 0; s < SNUM; ++s) {
                if (!((chosen >> s) & 1u) && dl[s] > best) { best = dl[s]; bi = s; }
            }
            chosen |= (1u << bi);
            s_ids[t * 4 + k] = sem_ids[b * SNUM + bi];
        }
        s_ids[t * 4 + 3] = word_ids[b];
    }
    __syncthreads();

    // Stage 2: all 256 threads gather float4 at h = 4t.
    const float third = 1.0f / 3.0f;
    float ax = 0.f, ay = 0.f, az = 0.f, aw = 0.f;
    #pragma unroll 8
    for (int w = 0; w < WNUM; ++w) {
        const float4 e0 = *(const float4*)(emb + (size_t)s_ids[w * 4 + 0] * HDIM + 4 * t);
        const float4 e1 = *(const float4*)(emb + (size_t)s_ids[w * 4 + 1] * HDIM + 4 * t);
        const float4 e2 = *(const float4*)(emb + (size_t)s_ids[w * 4 + 2] * HDIM + 4 * t);
        const float4 ew = *(const float4*)(emb + (size_t)s_ids[w * 4 + 3] * HDIM + 4 * t);
        ax += (e0.x + e1.x + e2.x) * third + ew.x;
        ay += (e0.y + e1.y + e2.y) * third + ew.y;
        az += (e0.z + e1.z + e2.z) * third + ew.z;
        aw += (e0.w + e1.w + e2.w) * third + ew.w;
    }
    const float scale = 0.5f / 16.0f;
    *(float4*)(out + (size_t)l * HDIM + 4 * t) =
        make_float4(ax * scale, ay * scale, az * scale, aw * scale);
}

extern "C" void kernel_launch(void* const* d_in, const int* in_sizes, int n_in,
                              void* d_out, int out_size, void* d_ws, size_t ws_size,
                              hipStream_t stream) {
    const float* emb  = (const float*)d_in[0];
    const int*   wids = (const int*)d_in[1];
    const int*   sids = (const int*)d_in[2];
    float*       out  = (float*)d_out;

    const int nb = in_sizes[1];          // L*W = 4096
    const int nj = in_sizes[2];          // L*W*S = 131072
    const int L  = out_size / HDIM;      // 256
    const int V  = in_sizes[0] / HDIM;   // 50257

    // ws layout (all 64B-aligned): dist[nj] f32 | perm[nj] i32 | hist[V] | cursor[V]
    char* wsb = (char*)d_ws;
    float* dist   = (float*)(wsb);
    int*   perm   = (int*)(wsb + (size_t)nj * 4);
    int*   hist   = (int*)(wsb + (size_t)nj * 8);
    int*   cursor = (int*)(wsb + (size_t)nj * 8 + (((size_t)V * 4 + 63) & ~63ull));

    hipMemsetAsync(hist, 0, (size_t)V * 4, stream);
    knn_hist_kernel<<<dim3((nj + 255) / 256), dim3(256), 0, stream>>>(sids, hist, nj);
    knn_scan_kernel<<<dim3(1), dim3(SCAN_T), 0, stream>>>(hist, cursor, V);
    knn_scatter_kernel<<<dim3((nj + 255) / 256), dim3(256), 0, stream>>>(sids, cursor, perm, nj);
    knn_dist_sorted_kernel<<<dim3(nj / 4), dim3(256), 0, stream>>>(emb, wids, sids, perm, dist);
    knn_outsel_kernel<<<dim3(L), dim3(256), 0, stream>>>(emb, dist, wids, sids, out);
}

// Round 13
// 90.864 us; speedup vs baseline: 2.1432x; 2.1432x over previous
//
#include <hip/hip_runtime.h>

// SememeEmbeddingKNN — R6-champion phase A + split select/output (R13).
//   emb      [V=50257, H=1024] f32   (206 MB table)
//   word_ids [L=256, W=16]     i32
//   sem_ids  [L=256, W=16, S=32] i32
//   out      [L, H] f32
//
// R12 -> R13: sorting (R12) regressed 2x (every XCD streams the whole table
// through its L2 + sort overhead); chunking (R11) was neutral. Phase A is
// pinned at ~3-4 TB/s on the random-row gather path -> restore the best
// measured phase A (R6: LDS word staging, wave per (b,octet), block per
// (b,quarter), 8-deep loads, ~73 us). Attack BC instead: it ran 256 blocks
// (1/CU). Split into B (select, 16 blocks, 1 thread/b) and C (output, 1024
// blocks = (l,quarter), 1 float/thread, 64 independent coalesced scalar
// loads) -> 4x parallelism on the L3-warm gather. No atomics, no out memset.

#define HDIM 1024
#define SNUM 32
#define WNUM 16
#define KNN  3

// ------- Phase A: partial distances (wave per b,octet; block per b,quarter)
__global__ __launch_bounds__(256) void knn_dist_kernel(
    const float* __restrict__ emb,
    const int*   __restrict__ word_ids,
    const int*   __restrict__ sem_ids,
    float*       __restrict__ dist_part,   // [4][nj]
    int nj)
{
    const int wave = threadIdx.x >> 6;     // octet 0..3
    const int lane = threadIdx.x & 63;
    const int blk  = blockIdx.x;           // b*4 + quarter
    const int b    = blk >> 2;
    const int quarter = blk & 3;

    __shared__ float s_w[256];

    const int wid = word_ids[b];
    s_w[threadIdx.x] = emb[(size_t)wid * HDIM + quarter * 256 + threadIdx.x];

    const int base_s = b * SNUM + wave * 8;
    const int col    = quarter * 256 + 4 * lane;

    const int4 sa = *(const int4*)(sem_ids + base_s);
    const int4 sb = *(const int4*)(sem_ids + base_s + 4);

    __syncthreads();
    const float4 w = *(const float4*)(s_w + 4 * lane);

    const int sids[8] = {sa.x, sa.y, sa.z, sa.w, sb.x, sb.y, sb.z, sb.w};
    float4 sv[8];
    #pragma unroll
    for (int k = 0; k < 8; ++k)
        sv[k] = *(const float4*)(emb + (size_t)sids[k] * HDIM + col);

    float d[8];
    #pragma unroll
    for (int k = 0; k < 8; ++k) {
        const float dx = sv[k].x - w.x;
        const float dy = sv[k].y - w.y;
        const float dz = sv[k].z - w.z;
        const float dw = sv[k].w - w.w;
        d[k] = (dx * dx + dy * dy) + (dz * dz + dw * dw);
    }

    #pragma unroll
    for (int k = 0; k < 8; ++k) {
        #pragma unroll
        for (int off = 32; off >= 1; off >>= 1)
            d[k] += __shfl_xor(d[k], off, 64);
    }

    if (lane == 0) {
        float* p = dist_part + (size_t)quarter * nj + base_s;
        *(float4*)(p + 0) = make_float4(d[0], d[1], d[2], d[3]);
        *(float4*)(p + 4) = make_float4(d[4], d[5], d[6], d[7]);
    }
}

// ---------------- Phase B: top-3 select (1 thread per b) ----------------
__global__ __launch_bounds__(256) void knn_select_kernel(
    const float* __restrict__ dist_part,   // [4][nj]
    const int*   __restrict__ word_ids,
    const int*   __restrict__ sem_ids,
    int*         __restrict__ sel,         // [nb][4]
    int nb, int nj)
{
    const int b = blockIdx.x * 256 + threadIdx.x;
    if (b >= nb) return;

    float4 acc[8];
    #pragma unroll
    for (int i = 0; i < 8; ++i) acc[i] = make_float4(0.f, 0.f, 0.f, 0.f);
    #pragma unroll
    for (int q = 0; q < 4; ++q) {
        const float4* p = (const float4*)(dist_part + (size_t)q * nj + b * SNUM);
        #pragma unroll
        for (int i = 0; i < 8; ++i) {
            const float4 v = p[i];
            acc[i].x += v.x; acc[i].y += v.y; acc[i].z += v.z; acc[i].w += v.w;
        }
    }
    float dl[SNUM];
    #pragma unroll
    for (int i = 0; i < 8; ++i) {
        dl[4 * i + 0] = acc[i].x;
        dl[4 * i + 1] = acc[i].y;
        dl[4 * i + 2] = acc[i].z;
        dl[4 * i + 3] = acc[i].w;
    }
    // Top-3 descending; strict '>' keeps earliest index (= jax top_k).
    unsigned chosen = 0;
    #pragma unroll
    for (int k = 0; k < KNN; ++k) {
        float best = -1.0f;
        int   bi   = 0;
        #pragma unroll
        for (int s = 0; s < SNUM; ++s) {
            if (!((chosen >> s) & 1u) && dl[s] > best) { best = dl[s]; bi = s; }
        }
        chosen |= (1u << bi);
        sel[b * 4 + k] = sem_ids[b * SNUM + bi];
    }
    sel[b * 4 + 3] = word_ids[b];
}

// -------- Phase C: gather + accumulate (block per (l, h-quarter)) --------
__global__ __launch_bounds__(256) void knn_out_kernel(
    const float* __restrict__ emb,
    const int*   __restrict__ sel,         // [nb][4]
    float*       __restrict__ out)
{
    const int l = blockIdx.x >> 2;
    const int q = blockIdx.x & 3;
    const int t = threadIdx.x;
    const int h = q * 256 + t;

    __shared__ int s_ids[WNUM * 4];
    if (t < WNUM * 4) s_ids[t] = sel[l * WNUM * 4 + t];
    __syncthreads();

    // 64 independent coalesced scalar loads (all ids known after barrier).
    const float third = 1.0f / 3.0f;
    float acc = 0.0f;
    #pragma unroll
    for (int w = 0; w < WNUM; ++w) {
        const float e0 = emb[(size_t)s_ids[w * 4 + 0] * HDIM + h];
        const float e1 = emb[(size_t)s_ids[w * 4 + 1] * HDIM + h];
        const float e2 = emb[(size_t)s_ids[w * 4 + 2] * HDIM + h];
        const float ew = emb[(size_t)s_ids[w * 4 + 3] * HDIM + h];
        acc += (e0 + e1 + e2) * third + ew;
    }
    out[(size_t)l * HDIM + h] = acc * (0.5f / 16.0f);
}

extern "C" void kernel_launch(void* const* d_in, const int* in_sizes, int n_in,
                              void* d_out, int out_size, void* d_ws, size_t ws_size,
                              hipStream_t stream) {
    const float* emb  = (const float*)d_in[0];
    const int*   wids = (const int*)d_in[1];
    const int*   sids = (const int*)d_in[2];
    float*       out  = (float*)d_out;

    const int nb = in_sizes[1];          // L*W = 4096
    const int nj = in_sizes[2];          // L*W*S = 131072
    const int L  = out_size / HDIM;      // 256

    float* dist_part = (float*)d_ws;                             // 4*nj f32 (2 MB)
    int*   sel       = (int*)((char*)d_ws + (size_t)4 * nj * 4); // nb*4 i32

    knn_dist_kernel<<<dim3(nb * 4), dim3(256), 0, stream>>>(emb, wids, sids, dist_part, nj);
    knn_select_kernel<<<dim3((nb + 255) / 256), dim3(256), 0, stream>>>(dist_part, wids, sids, sel, nb, nj);
    knn_out_kernel<<<dim3(L * 4), dim3(256), 0, stream>>>(emb, sel, out);
}